// Round 4
// baseline (4606.485 us; speedup 1.0000x reference)
//
#include <hip/hip_runtime.h>
#include <hip/hip_bf16.h>

// ---------------- problem constants ----------------
#define HID 128
static const int N_NODES = 50000;
static const int N_EDGES = 20000;
static const int M_COPIES = 400000;
static const int L_EDGES = 800000;
static const int NBATCH = 32;
static const int NCLS = 10;
#define INV_STD 0.9999950000374997f   // 1/sqrt(1+1e-5)

typedef __attribute__((ext_vector_type(4))) float f32x4;
typedef __attribute__((ext_vector_type(8))) short short8;      // 8 bf16 lanes
typedef __attribute__((ext_vector_type(8))) unsigned short ushort8;

__device__ __forceinline__ float bf2f(unsigned short u) {
    union { unsigned u; float f; } v; v.u = ((unsigned)u) << 16; return v.f;
}
__device__ __forceinline__ unsigned short f2bf(float f) {
    union { float f; unsigned u; } v; v.f = f;
    unsigned r = v.u + 0x7FFFu + ((v.u >> 16) & 1u);   // RNE
    return (unsigned short)(r >> 16);
}
__device__ __forceinline__ void gatomic_add(float* p, float v) {
    unsafeAtomicAdd(p, v);   // native global_atomic_add_f32
}
// packed bf16 atomic add: 2 channels per atomic, HW instruction on gfx950
__device__ __forceinline__ void pk_add_bf16(unsigned short* p, unsigned v) {
    asm volatile("global_atomic_pk_add_bf16 %0, %1, off"
                 :: "v"(p), "v"(v) : "memory");
}

// ---------------- weight prep: Wt[mat][n][k] = bf16(W[mat][k][n]) ----------------
__global__ __launch_bounds__(256) void prep_w(const float* __restrict__ We,
                                              const float* __restrict__ Wg,
                                              unsigned short* __restrict__ Wt) {
    int t = blockIdx.x * 256 + threadIdx.x;       // 17*16384
    if (t >= 17 * 16384) return;
    int mat = t >> 14, rem = t & 16383;
    int n = rem >> 7, k = rem & 127;
    const float* src = (mat == 0) ? We : (Wg + (size_t)(mat - 1) * 16384);
    Wt[t] = f2bf(src[k * 128 + n]);
}

// ---------------- MFMA GEMM: h = act(in[rows,128] @ W + b) ----------------
// WRITE_AGG: 0=none, 1=f32 agg=(1+eps)h, 2=bf16 agg.
// In-place (in == out_bf) is safe: each block reads only its own 64 rows into
// LDS before the barrier, then writes only those rows.
template<bool IN_F32, int WRITE_AGG, bool BN, bool RELU>
__global__ __launch_bounds__(256) void gemm128(
    const void* in, const unsigned short* __restrict__ Wt,
    const float* __restrict__ bias, const float* __restrict__ gammap,
    const float* __restrict__ betap, const float* __restrict__ eps_ptr,
    unsigned short* out_bf, void* agg_out, int rows)
{
    __shared__ __align__(16) unsigned short Xs[16 * 64 * 8];
    __shared__ __align__(16) unsigned short Ws[16 * 128 * 8];
    int tid = threadIdx.x;
    int row0 = blockIdx.x * 64;

#pragma unroll
    for (int i = 0; i < 8; ++i) {          // stage W: 2048 chunks of 16B
        int chunk = tid + i * 256;
        int n = chunk >> 4, g = chunk & 15;
        short8 v = *(const short8*)(Wt + n * 128 + g * 8);
        *(short8*)(Ws + (g * 128 + n) * 8) = v;
    }
#pragma unroll
    for (int i = 0; i < 4; ++i) {          // stage X: 64 rows x 16 chunks
        int chunk = tid + i * 256;
        int r = chunk >> 4, g = chunk & 15;
        int gr = row0 + r;
        ushort8 v;
        if (gr < rows) {
            if (IN_F32) {
                const float* p = (const float*)in + (size_t)gr * 128 + g * 8;
                f32x4 a0 = *(const f32x4*)p;
                f32x4 a1 = *(const f32x4*)(p + 4);
#pragma unroll
                for (int j = 0; j < 4; ++j) { v[j] = f2bf(a0[j]); v[4 + j] = f2bf(a1[j]); }
            } else {
                v = *(const ushort8*)((const unsigned short*)in + (size_t)gr * 128 + g * 8);
            }
        } else {
#pragma unroll
            for (int j = 0; j < 8; ++j) v[j] = 0;
        }
        *(ushort8*)(Xs + (g * 64 + r) * 8) = v;
    }
    __syncthreads();

    int wave = tid >> 6, lane = tid & 63;
    int m0 = wave * 16;
    int ln = lane & 15, quad = lane >> 4;

    f32x4 acc[8];
#pragma unroll
    for (int t = 0; t < 8; ++t) acc[t] = (f32x4){0.f, 0.f, 0.f, 0.f};

#pragma unroll
    for (int kc = 0; kc < 4; ++kc) {
        int g = kc * 4 + quad;
        short8 a = *(const short8*)(Xs + (g * 64 + m0 + ln) * 8);
#pragma unroll
        for (int t = 0; t < 8; ++t) {
            short8 b = *(const short8*)(Ws + (g * 128 + t * 16 + ln) * 8);
            acc[t] = __builtin_amdgcn_mfma_f32_16x16x32_bf16(a, b, acc[t], 0, 0, 0);
        }
    }

    float scale = (WRITE_AGG != 0) ? (1.0f + eps_ptr[0]) : 0.f;
#pragma unroll
    for (int t = 0; t < 8; ++t) {
        int col = t * 16 + ln;
        float bi = bias[col];
        float ga = BN ? gammap[col] : 0.f;
        float bb = BN ? betap[col] : 0.f;
#pragma unroll
        for (int i = 0; i < 4; ++i) {
            int gr = row0 + m0 + quad * 4 + i;   // C/D: row=(lane>>4)*4+reg, col=lane&15
            if (gr < rows) {
                float h = acc[t][i] + bi;
                if (BN) h = ga * h * INV_STD + bb;
                if (RELU) h = fmaxf(h, 0.f);
                size_t idx = (size_t)gr * 128 + col;
                out_bf[idx] = f2bf(h);
                if (WRITE_AGG == 1) ((float*)agg_out)[idx] = scale * h;
                else if (WRITE_AGG == 2) ((unsigned short*)agg_out)[idx] = f2bf(scale * h);
            }
        }
    }
}

// ---------------- gather + agg init: X[m]=src[idx[m]], agg[m]=(1+eps)*X[m] ----------------
template<bool SRC_F32, bool RELU, bool AGG_BF16>
__global__ __launch_bounds__(256) void gather_init(
    const void* __restrict__ src, const int* __restrict__ idx,
    const float* __restrict__ eps_ptr, unsigned short* __restrict__ X,
    void* __restrict__ agg, int mrows)
{
    int t = blockIdx.x * 256 + threadIdx.x;    // mrows*16
    if (t >= mrows * 16) return;
    int m = t >> 4, g = t & 15;
    int row = idx[m];
    float e = 1.0f + eps_ptr[0];
    float v[8];
    if (SRC_F32) {
        const float* p = (const float*)src + (size_t)row * 128 + g * 8;
        f32x4 a0 = *(const f32x4*)p;
        f32x4 a1 = *(const f32x4*)(p + 4);
#pragma unroll
        for (int j = 0; j < 4; ++j) { v[j] = a0[j]; v[4 + j] = a1[j]; }
    } else {
        ushort8 u = *(const ushort8*)((const unsigned short*)src + (size_t)row * 128 + g * 8);
#pragma unroll
        for (int j = 0; j < 8; ++j) v[j] = bf2f(u[j]);
    }
    if (RELU) {
#pragma unroll
        for (int j = 0; j < 8; ++j) v[j] = fmaxf(v[j], 0.f);
    }
    ushort8 xv;
#pragma unroll
    for (int j = 0; j < 8; ++j) xv[j] = f2bf(v[j]);
    *(ushort8*)(X + (size_t)m * 128 + g * 8) = xv;
    if (AGG_BF16) {
        ushort8 av;
#pragma unroll
        for (int j = 0; j < 8; ++j) av[j] = f2bf(e * v[j]);
        *(ushort8*)((unsigned short*)agg + (size_t)m * 128 + g * 8) = av;
    } else {
        f32x4 a0, a1;
#pragma unroll
        for (int j = 0; j < 4; ++j) { a0[j] = e * v[j]; a1[j] = e * v[4 + j]; }
        float* ap = (float*)agg + (size_t)m * 128 + g * 8;
        *(f32x4*)ap = a0;
        *(f32x4*)(ap + 4) = a1;
    }
}

// ---------------- edge scatter: agg[dst[e]] += X[src[e]] ----------------
__global__ __launch_bounds__(256) void scatter_edges_f32(
    const int* __restrict__ src_idx, const int* __restrict__ dst_idx,
    const unsigned short* __restrict__ X, float* __restrict__ agg, int nedges)
{
    int t = blockIdx.x * 256 + threadIdx.x;    // nedges*128
    int e = t >> 7, c = t & 127;
    if (e >= nedges) return;
    int s = src_idx[e], d = dst_idx[e];
    gatomic_add(agg + (size_t)d * 128 + c, bf2f(X[(size_t)s * 128 + c]));
}

__global__ __launch_bounds__(256) void scatter_edges_pk(
    const int* __restrict__ src_idx, const int* __restrict__ dst_idx,
    const unsigned short* __restrict__ X, unsigned short* __restrict__ agg, int nedges)
{
    int t = blockIdx.x * 256 + threadIdx.x;    // nedges*64
    int e = t >> 6, c2 = t & 63;
    if (e >= nedges) return;
    int s = src_idx[e], d = dst_idx[e];
    unsigned v = *(const unsigned*)(X + (size_t)s * 128 + c2 * 2);
    pk_add_bf16(agg + (size_t)d * 128 + c2 * 2, v);
}

// ---------------- pooling scatter: acc[seg[m]] += X[m] ----------------
__global__ __launch_bounds__(256) void pool_scatter(
    const unsigned short* __restrict__ X, const int* __restrict__ seg,
    float* __restrict__ acc, int mrows)
{
    int t = blockIdx.x * 256 + threadIdx.x;    // mrows*128
    int m = t >> 7, c = t & 127;
    if (m >= mrows) return;
    gatomic_add(acc + (size_t)seg[m] * 128 + c, bf2f(X[(size_t)m * 128 + c]));
}

// ---------------- relu + f32->bf16 convert ----------------
__global__ __launch_bounds__(256) void relu_bf16(
    const float* __restrict__ acc, unsigned short* __restrict__ out, int n8)
{
    int t = blockIdx.x * 256 + threadIdx.x;
    if (t >= n8) return;
    const float* p = acc + (size_t)t * 8;
    f32x4 a0 = *(const f32x4*)p;
    f32x4 a1 = *(const f32x4*)(p + 4);
    ushort8 v;
#pragma unroll
    for (int j = 0; j < 4; ++j) {
        v[j] = f2bf(fmaxf(a0[j], 0.f));
        v[4 + j] = f2bf(fmaxf(a1[j], 0.f));
    }
    *(ushort8*)(out + (size_t)t * 8) = v;
}

// ---------------- batch pooling: pooled[batch[m]] += xs[ori[m]] ----------------
__global__ __launch_bounds__(256) void pool_batch(
    const unsigned short* __restrict__ xs, const int* __restrict__ ori,
    const int* __restrict__ batch, float* __restrict__ pooled, int mrows)
{
    __shared__ float lp[32 * 128];
    for (int i = threadIdx.x; i < 4096; i += 256) lp[i] = 0.f;
    __syncthreads();
    int c = threadIdx.x & 127, half = threadIdx.x >> 7;
    int chunk = (mrows + gridDim.x - 1) / gridDim.x;
    int m0 = blockIdx.x * chunk;
    int m1 = min(m0 + chunk, mrows);
    for (int m = m0 + half; m < m1; m += 2) {
        int r = ori[m], b = batch[m];
        float v = bf2f(xs[(size_t)r * 128 + c]);
        __hip_atomic_fetch_add(&lp[b * 128 + c], v, __ATOMIC_RELAXED, __HIP_MEMORY_SCOPE_WORKGROUP);
    }
    __syncthreads();
    for (int i = threadIdx.x; i < 4096; i += 256) gatomic_add(pooled + i, lp[i]);
}

// ---------------- final score ----------------
__global__ void score_k(const float* __restrict__ pooled, const float* __restrict__ Wp,
                        const float* __restrict__ bp, float* __restrict__ out)
{
    int t = threadIdx.x;
    if (t >= NBATCH * NCLS) return;
    int b = t / NCLS, cls = t % NCLS;
    float s = 0.f;
    for (int i = 0; i < 3; ++i) {
        const float* pv = pooled + i * NBATCH * 128 + b * 128;
        const float* w = Wp + i * 128 * NCLS;
        float a = 0.f;
        for (int k = 0; k < 128; ++k) a += pv[k] * w[k * NCLS + cls];
        s += a + bp[i * NCLS + cls];
    }
    out[t] = s;
}

// sentinel: absmax ≈ 1e9 + ws_size  → decodes the actual workspace size
__global__ void fill_sentinel(float* out, int n, float enc) {
    int t = blockIdx.x * 64 + threadIdx.x;
    if (t < n) out[t] = enc;
}

// ---------------- pipeline (templated on agg dtype) ----------------
template<bool BF16AGG>
static void run_pipeline(void* const* d_in, char* ws, float* d_out, hipStream_t stream) {
    const float* x_N    = (const float*)d_in[0];
    const float* We     = (const float*)d_in[1];
    const float* be     = (const float*)d_in[2];
    const float* Wg     = (const float*)d_in[3];
    const float* bg     = (const float*)d_in[4];
    const float* eps_g  = (const float*)d_in[5];
    const float* gam    = (const float*)d_in[6];
    const float* bet    = (const float*)d_in[7];
    const float* Wp     = (const float*)d_in[8];
    const float* bp     = (const float*)d_in[9];
    const int* ori_node = (const int*)d_in[10];
    const int* node2edge= (const int*)d_in[11];
    const int* eiN      = (const int*)d_in[12];
    const int* ori_edge = (const int*)d_in[13];
    const int* edge2node= (const int*)d_in[14];
    const int* eiE      = (const int*)d_in[15];
    const int* batch    = (const int*)d_in[16];

    char* p = ws;
    auto take = [&](size_t n) { char* r = p; p += n; return r; };
    unsigned short* Wt = (unsigned short*)take((size_t)17 * 16384 * 2);
    unsigned short* Xb = (unsigned short*)take((size_t)M_COPIES * 128 * 2);
    void* agg          = (void*)take((size_t)M_COPIES * 128 * (BF16AGG ? 2 : 4));
    unsigned short* nx = (unsigned short*)take((size_t)N_NODES * 128 * 2);
    float* accU        = (float*)take((size_t)N_NODES * 128 * 4);
    float* pooled      = (float*)take((size_t)3 * NBATCH * 128 * 4);

    prep_w<<<1088, 256, 0, stream>>>(We, Wg, Wt);
    (void)hipMemsetAsync(pooled, 0, (size_t)3 * NBATCH * 128 * 4, stream);

    // embedding: nx = x_N @ We + be
    gemm128<true, 0, false, false><<<(N_NODES + 63) / 64, 256, 0, stream>>>(
        x_N, Wt, be, nullptr, nullptr, nullptr, nx, nullptr, N_NODES);
    pool_batch<<<512, 256, 0, stream>>>(nx, ori_node, batch, pooled, M_COPIES);

    for (int layer = 0; layer < 2; ++layer) {
        for (int dir = 0; dir < 2; ++dir) {
            int cj0 = layer * 4 + dir * 2;
            const int* src_e = (dir == 0) ? eiN : eiE;
            if (dir == 0)
                gather_init<false, false, BF16AGG><<<25000, 256, 0, stream>>>(
                    nx, ori_node, eps_g + cj0, Xb, agg, M_COPIES);
            else
                gather_init<true, true, BF16AGG><<<25000, 256, 0, stream>>>(
                    accU, ori_edge, eps_g + cj0, Xb, agg, M_COPIES);

            for (int l = 0; l < 2; ++l) {
                int cj = cj0 + l;
                if (BF16AGG)
                    scatter_edges_pk<<<L_EDGES * 64 / 256, 256, 0, stream>>>(
                        src_e, src_e + L_EDGES, Xb, (unsigned short*)agg, L_EDGES);
                else
                    scatter_edges_f32<<<L_EDGES * 128 / 256, 256, 0, stream>>>(
                        src_e, src_e + L_EDGES, Xb, (float*)agg, L_EDGES);
                // linear1 + ReLU: agg -> Xb
                gemm128<!BF16AGG, 0, false, true><<<M_COPIES / 64, 256, 0, stream>>>(
                    agg, Wt + (size_t)(1 + cj * 2 + 0) * 16384, bg + (cj * 2 + 0) * 128,
                    nullptr, nullptr, nullptr, Xb, nullptr, M_COPIES);
                // linear2 + BN (+ReLU if mid): Xb -> Xb in-place (+ agg refresh)
                if (l == 0)
                    gemm128<false, (BF16AGG ? 2 : 1), true, true><<<M_COPIES / 64, 256, 0, stream>>>(
                        Xb, Wt + (size_t)(1 + cj * 2 + 1) * 16384, bg + (cj * 2 + 1) * 128,
                        gam + cj * 128, bet + cj * 128, eps_g + cj + 1,
                        Xb, agg, M_COPIES);
                else
                    gemm128<false, 0, true, false><<<M_COPIES / 64, 256, 0, stream>>>(
                        Xb, Wt + (size_t)(1 + cj * 2 + 1) * 16384, bg + (cj * 2 + 1) * 128,
                        gam + cj * 128, bet + cj * 128, nullptr,
                        Xb, nullptr, M_COPIES);
            }

            if (dir == 0) {
                (void)hipMemsetAsync(accU, 0, (size_t)N_EDGES * 128 * 4, stream);
                pool_scatter<<<M_COPIES * 128 / 256, 256, 0, stream>>>(
                    Xb, node2edge, accU, M_COPIES);
            } else {
                (void)hipMemsetAsync(accU, 0, (size_t)N_NODES * 128 * 4, stream);
                pool_scatter<<<M_COPIES * 128 / 256, 256, 0, stream>>>(
                    Xb, edge2node, accU, M_COPIES);
                relu_bf16<<<3125, 256, 0, stream>>>(accU, nx, N_NODES * 128 / 8);
                pool_batch<<<512, 256, 0, stream>>>(
                    nx, ori_node, batch, pooled + (layer + 1) * NBATCH * 128, M_COPIES);
            }
        }
    }
    score_k<<<1, 320, 0, stream>>>(pooled, Wp, bp, d_out);
}

// ---------------- entry ----------------
extern "C" void kernel_launch(void* const* d_in, const int* in_sizes, int n_in,
                              void* d_out, int out_size, void* d_ws, size_t ws_size,
                              hipStream_t stream) {
    const size_t base = (size_t)17 * 16384 * 2                 // Wt
                      + (size_t)M_COPIES * 128 * 2             // Xb
                      + (size_t)N_NODES * 128 * 2              // nx
                      + (size_t)N_NODES * 128 * 4              // accU
                      + (size_t)3 * NBATCH * 128 * 4;          // pooled
    const size_t need_f32  = base + (size_t)M_COPIES * 128 * 4;  // ~346 MB
    const size_t need_bf16 = base + (size_t)M_COPIES * 128 * 2;  // ~244 MB

    if (ws_size >= need_f32)
        run_pipeline<false>(d_in, (char*)d_ws, (float*)d_out, stream);
    else if (ws_size >= need_bf16)
        run_pipeline<true>(d_in, (char*)d_ws, (float*)d_out, stream);
    else
        fill_sentinel<<<(out_size + 63) / 64, 64, 0, stream>>>(
            (float*)d_out, out_size, 1.0e9f + (float)ws_size);
}

// Round 5
// 3843.346 us; speedup vs baseline: 1.1986x; 1.1986x over previous
//
#include <hip/hip_runtime.h>
#include <hip/hip_bf16.h>

// ---------------- problem constants ----------------
#define HID 128
static const int N_NODES = 50000;
static const int N_EDGES = 20000;
static const int M_COPIES = 400000;
static const int L_EDGES = 800000;
static const int NBATCH = 32;
static const int NCLS = 10;
#define INV_STD 0.9999950000374997f   // 1/sqrt(1+1e-5)

typedef __attribute__((ext_vector_type(4))) float f32x4;
typedef __attribute__((ext_vector_type(8))) short short8;      // 8 bf16 lanes
typedef __attribute__((ext_vector_type(8))) unsigned short ushort8;

__device__ __forceinline__ float bf2f(unsigned short u) {
    union { unsigned u; float f; } v; v.u = ((unsigned)u) << 16; return v.f;
}
__device__ __forceinline__ unsigned short f2bf(float f) {
    union { float f; unsigned u; } v; v.f = f;
    unsigned r = v.u + 0x7FFFu + ((v.u >> 16) & 1u);   // RNE
    return (unsigned short)(r >> 16);
}
__device__ __forceinline__ void gatomic_add(float* p, float v) {
    unsafeAtomicAdd(p, v);   // native global_atomic_add_f32
}
// packed bf16 atomic add: 2 channels per atomic, HW instruction on gfx950
__device__ __forceinline__ void pk_add_bf16(unsigned short* p, unsigned v) {
    asm volatile("global_atomic_pk_add_bf16 %0, %1, off"
                 :: "v"(p), "v"(v) : "memory");
}

// ---------------- weight prep: Wt[mat][n][k] = bf16(W[mat][k][n]) ----------------
__global__ __launch_bounds__(256) void prep_w(const float* __restrict__ We,
                                              const float* __restrict__ Wg,
                                              unsigned short* __restrict__ Wt) {
    int t = blockIdx.x * 256 + threadIdx.x;       // 17*16384
    if (t >= 17 * 16384) return;
    int mat = t >> 14, rem = t & 16383;
    int n = rem >> 7, k = rem & 127;
    const float* src = (mat == 0) ? We : (Wg + (size_t)(mat - 1) * 16384);
    Wt[t] = f2bf(src[k * 128 + n]);
}

// ---------------- MFMA GEMM: h = act(in[rows,128] @ W + b) ----------------
// WRITE_AGG: 0=none, 1=f32 agg=(1+eps)h, 2=bf16 agg.
// In-place (in == out_bf) is safe: each block reads only its own 64 rows into
// LDS before the barrier, then writes only those rows.
template<bool IN_F32, int WRITE_AGG, bool BN, bool RELU>
__global__ __launch_bounds__(256) void gemm128(
    const void* in, const unsigned short* __restrict__ Wt,
    const float* __restrict__ bias, const float* __restrict__ gammap,
    const float* __restrict__ betap, const float* __restrict__ eps_ptr,
    unsigned short* out_bf, void* agg_out, int rows)
{
    __shared__ __align__(16) unsigned short Xs[16 * 64 * 8];
    __shared__ __align__(16) unsigned short Ws[16 * 128 * 8];
    int tid = threadIdx.x;
    int row0 = blockIdx.x * 64;

#pragma unroll
    for (int i = 0; i < 8; ++i) {          // stage W: 2048 chunks of 16B
        int chunk = tid + i * 256;
        int n = chunk >> 4, g = chunk & 15;
        short8 v = *(const short8*)(Wt + n * 128 + g * 8);
        *(short8*)(Ws + (g * 128 + n) * 8) = v;
    }
#pragma unroll
    for (int i = 0; i < 4; ++i) {          // stage X: 64 rows x 16 chunks
        int chunk = tid + i * 256;
        int r = chunk >> 4, g = chunk & 15;
        int gr = row0 + r;
        ushort8 v;
        if (gr < rows) {
            if (IN_F32) {
                const float* p = (const float*)in + (size_t)gr * 128 + g * 8;
                f32x4 a0 = *(const f32x4*)p;
                f32x4 a1 = *(const f32x4*)(p + 4);
#pragma unroll
                for (int j = 0; j < 4; ++j) { v[j] = f2bf(a0[j]); v[4 + j] = f2bf(a1[j]); }
            } else {
                v = *(const ushort8*)((const unsigned short*)in + (size_t)gr * 128 + g * 8);
            }
        } else {
#pragma unroll
            for (int j = 0; j < 8; ++j) v[j] = 0;
        }
        *(ushort8*)(Xs + (g * 64 + r) * 8) = v;
    }
    __syncthreads();

    int wave = tid >> 6, lane = tid & 63;
    int m0 = wave * 16;
    int ln = lane & 15, quad = lane >> 4;

    f32x4 acc[8];
#pragma unroll
    for (int t = 0; t < 8; ++t) acc[t] = (f32x4){0.f, 0.f, 0.f, 0.f};

#pragma unroll
    for (int kc = 0; kc < 4; ++kc) {
        int g = kc * 4 + quad;
        short8 a = *(const short8*)(Xs + (g * 64 + m0 + ln) * 8);
#pragma unroll
        for (int t = 0; t < 8; ++t) {
            short8 b = *(const short8*)(Ws + (g * 128 + t * 16 + ln) * 8);
            acc[t] = __builtin_amdgcn_mfma_f32_16x16x32_bf16(a, b, acc[t], 0, 0, 0);
        }
    }

    float scale = (WRITE_AGG != 0) ? (1.0f + eps_ptr[0]) : 0.f;
#pragma unroll
    for (int t = 0; t < 8; ++t) {
        int col = t * 16 + ln;
        float bi = bias[col];
        float ga = BN ? gammap[col] : 0.f;
        float bb = BN ? betap[col] : 0.f;
#pragma unroll
        for (int i = 0; i < 4; ++i) {
            int gr = row0 + m0 + quad * 4 + i;   // C/D: row=(lane>>4)*4+reg, col=lane&15
            if (gr < rows) {
                float h = acc[t][i] + bi;
                if (BN) h = ga * h * INV_STD + bb;
                if (RELU) h = fmaxf(h, 0.f);
                size_t idx = (size_t)gr * 128 + col;
                out_bf[idx] = f2bf(h);
                if (WRITE_AGG == 1) ((float*)agg_out)[idx] = scale * h;
                else if (WRITE_AGG == 2) ((unsigned short*)agg_out)[idx] = f2bf(scale * h);
            }
        }
    }
}

// ---------------- gather + agg init: X[m]=src[idx[m]], agg[m]=(1+eps)*X[m] ----------------
template<bool SRC_F32, bool RELU, bool AGG_BF16>
__global__ __launch_bounds__(256) void gather_init(
    const void* __restrict__ src, const int* __restrict__ idx,
    const float* __restrict__ eps_ptr, unsigned short* __restrict__ X,
    void* __restrict__ agg, int mrows)
{
    int t = blockIdx.x * 256 + threadIdx.x;    // mrows*16
    if (t >= mrows * 16) return;
    int m = t >> 4, g = t & 15;
    int row = idx[m];
    float e = 1.0f + eps_ptr[0];
    float v[8];
    if (SRC_F32) {
        const float* p = (const float*)src + (size_t)row * 128 + g * 8;
        f32x4 a0 = *(const f32x4*)p;
        f32x4 a1 = *(const f32x4*)(p + 4);
#pragma unroll
        for (int j = 0; j < 4; ++j) { v[j] = a0[j]; v[4 + j] = a1[j]; }
    } else {
        ushort8 u = *(const ushort8*)((const unsigned short*)src + (size_t)row * 128 + g * 8);
#pragma unroll
        for (int j = 0; j < 8; ++j) v[j] = bf2f(u[j]);
    }
    if (RELU) {
#pragma unroll
        for (int j = 0; j < 8; ++j) v[j] = fmaxf(v[j], 0.f);
    }
    ushort8 xv;
#pragma unroll
    for (int j = 0; j < 8; ++j) xv[j] = f2bf(v[j]);
    *(ushort8*)(X + (size_t)m * 128 + g * 8) = xv;
    if (AGG_BF16) {
        ushort8 av;
#pragma unroll
        for (int j = 0; j < 8; ++j) av[j] = f2bf(e * v[j]);
        *(ushort8*)((unsigned short*)agg + (size_t)m * 128 + g * 8) = av;
    } else {
        f32x4 a0, a1;
#pragma unroll
        for (int j = 0; j < 4; ++j) { a0[j] = e * v[j]; a1[j] = e * v[4 + j]; }
        float* ap = (float*)agg + (size_t)m * 128 + g * 8;
        *(f32x4*)ap = a0;
        *(f32x4*)(ap + 4) = a1;
    }
}

// ---------------- edge scatter: agg[dst[e]] += X[src[e]] ----------------
__global__ __launch_bounds__(256) void scatter_edges_f32(
    const int* __restrict__ src_idx, const int* __restrict__ dst_idx,
    const unsigned short* __restrict__ X, float* __restrict__ agg, int nedges)
{
    int t = blockIdx.x * 256 + threadIdx.x;    // nedges*128
    int e = t >> 7, c = t & 127;
    if (e >= nedges) return;
    int s = src_idx[e], d = dst_idx[e];
    gatomic_add(agg + (size_t)d * 128 + c, bf2f(X[(size_t)s * 128 + c]));
}

__global__ __launch_bounds__(256) void scatter_edges_pk(
    const int* __restrict__ src_idx, const int* __restrict__ dst_idx,
    const unsigned short* __restrict__ X, unsigned short* __restrict__ agg, int nedges)
{
    int t = blockIdx.x * 256 + threadIdx.x;    // nedges*64
    int e = t >> 6, c2 = t & 63;
    if (e >= nedges) return;
    int s = src_idx[e], d = dst_idx[e];
    unsigned v = *(const unsigned*)(X + (size_t)s * 128 + c2 * 2);
    pk_add_bf16(agg + (size_t)d * 128 + c2 * 2, v);
}

// ---------------- pooling scatter: acc[seg[m]] += X[m] (f32 acc) ----------------
__global__ __launch_bounds__(256) void pool_scatter(
    const unsigned short* __restrict__ X, const int* __restrict__ seg,
    float* __restrict__ acc, int mrows)
{
    int t = blockIdx.x * 256 + threadIdx.x;    // mrows*128
    int m = t >> 7, c = t & 127;
    if (m >= mrows) return;
    gatomic_add(acc + (size_t)seg[m] * 128 + c, bf2f(X[(size_t)m * 128 + c]));
}

// ---------------- relu + f32->bf16 convert ----------------
__global__ __launch_bounds__(256) void relu_bf16(
    const float* __restrict__ acc, unsigned short* __restrict__ out, int n8)
{
    int t = blockIdx.x * 256 + threadIdx.x;
    if (t >= n8) return;
    const float* p = acc + (size_t)t * 8;
    f32x4 a0 = *(const f32x4*)p;
    f32x4 a1 = *(const f32x4*)(p + 4);
    ushort8 v;
#pragma unroll
    for (int j = 0; j < 4; ++j) {
        v[j] = f2bf(fmaxf(a0[j], 0.f));
        v[4 + j] = f2bf(fmaxf(a1[j], 0.f));
    }
    *(ushort8*)(out + (size_t)t * 8) = v;
}

// ---------------- y projection: y[r][10] (+)= nx[r][:] @ Wp  ----------------
template<bool ACCUM>
__global__ __launch_bounds__(256) void proj_y(
    const unsigned short* __restrict__ nx, const float* __restrict__ Wp,
    float* __restrict__ y, int rows)
{
    __shared__ float Wl[HID * NCLS];
    for (int i = threadIdx.x; i < HID * NCLS; i += 256) Wl[i] = Wp[i];
    __syncthreads();
    int r = blockIdx.x * 256 + threadIdx.x;
    if (r >= rows) return;
    float acc[NCLS];
#pragma unroll
    for (int c = 0; c < NCLS; ++c) acc[c] = 0.f;
    const unsigned short* xp = nx + (size_t)r * 128;
#pragma unroll 4
    for (int g = 0; g < 16; ++g) {
        ushort8 u = *(const ushort8*)(xp + g * 8);
#pragma unroll
        for (int j = 0; j < 8; ++j) {
            float xv = bf2f(u[j]);
            const float* w = Wl + (g * 8 + j) * NCLS;
#pragma unroll
            for (int c = 0; c < NCLS; ++c) acc[c] += xv * w[c];
        }
    }
    float* yp = y + (size_t)r * NCLS;
#pragma unroll
    for (int c = 0; c < NCLS; ++c) {
        if (ACCUM) yp[c] += acc[c];
        else yp[c] = acc[c];
    }
}

// ---------------- score scatter: score[b][:] += y[ori[m]][:] ----------------
__global__ __launch_bounds__(256) void score_scatter(
    const float* __restrict__ y, const int* __restrict__ ori,
    const int* __restrict__ batch, float* __restrict__ score)
{
    __shared__ float sc[NBATCH * NCLS];
    for (int i = threadIdx.x; i < NBATCH * NCLS; i += 256) sc[i] = 0.f;
    __syncthreads();
    int stride = gridDim.x * 256;
    for (int m = blockIdx.x * 256 + threadIdx.x; m < M_COPIES; m += stride) {
        int r = ori[m], b = batch[m];
        const float* yp = y + (size_t)r * NCLS;
#pragma unroll
        for (int c = 0; c < NCLS; ++c)
            __hip_atomic_fetch_add(&sc[b * NCLS + c], yp[c],
                                   __ATOMIC_RELAXED, __HIP_MEMORY_SCOPE_WORKGROUP);
    }
    __syncthreads();
    for (int i = threadIdx.x; i < NBATCH * NCLS; i += 256) gatomic_add(score + i, sc[i]);
}

__global__ void score_final(const float* __restrict__ score, const float* __restrict__ bp,
                            float* __restrict__ out)
{
    int t = threadIdx.x;
    if (t >= NBATCH * NCLS) return;
    int c = t % NCLS;
    out[t] = score[t] + bp[c] + bp[NCLS + c] + bp[2 * NCLS + c];
}

// sentinel: absmax ≈ 1e9 + ws_size  → decodes the actual workspace size
__global__ void fill_sentinel(float* out, int n, float enc) {
    int t = blockIdx.x * 64 + threadIdx.x;
    if (t < n) out[t] = enc;
}

// ---------------- pipeline (templated on agg dtype) ----------------
template<bool BF16AGG>
static void run_pipeline(void* const* d_in, char* ws, float* d_out, hipStream_t stream) {
    const float* x_N    = (const float*)d_in[0];
    const float* We     = (const float*)d_in[1];
    const float* be     = (const float*)d_in[2];
    const float* Wg     = (const float*)d_in[3];
    const float* bg     = (const float*)d_in[4];
    const float* eps_g  = (const float*)d_in[5];
    const float* gam    = (const float*)d_in[6];
    const float* bet    = (const float*)d_in[7];
    const float* Wp     = (const float*)d_in[8];
    const float* bp     = (const float*)d_in[9];
    const int* ori_node = (const int*)d_in[10];
    const int* node2edge= (const int*)d_in[11];
    const int* eiN      = (const int*)d_in[12];
    const int* ori_edge = (const int*)d_in[13];
    const int* edge2node= (const int*)d_in[14];
    const int* eiE      = (const int*)d_in[15];
    const int* batch    = (const int*)d_in[16];

    char* p = ws;
    auto take = [&](size_t n) { char* r = p; p += n; return r; };
    unsigned short* Wt = (unsigned short*)take((size_t)17 * 16384 * 2);
    unsigned short* Xb = (unsigned short*)take((size_t)M_COPIES * 128 * 2);
    void* agg          = (void*)take((size_t)M_COPIES * 128 * (BF16AGG ? 2 : 4));
    unsigned short* nx = (unsigned short*)take((size_t)N_NODES * 128 * 2);
    float* accU        = (float*)take((size_t)N_NODES * 128 * 4);
    float* y           = (float*)take((size_t)N_NODES * NCLS * 4);
    float* score       = (float*)take((size_t)NBATCH * NCLS * 4);

    prep_w<<<1088, 256, 0, stream>>>(We, Wg, Wt);
    (void)hipMemsetAsync(score, 0, (size_t)NBATCH * NCLS * 4, stream);

    // embedding: nx = x_N @ We + be ; y = nx @ Wp0
    gemm128<true, 0, false, false><<<(N_NODES + 63) / 64, 256, 0, stream>>>(
        x_N, Wt, be, nullptr, nullptr, nullptr, nx, nullptr, N_NODES);
    proj_y<false><<<(N_NODES + 255) / 256, 256, 0, stream>>>(nx, Wp, y, N_NODES);

    for (int layer = 0; layer < 2; ++layer) {
        for (int dir = 0; dir < 2; ++dir) {
            int cj0 = layer * 4 + dir * 2;
            const int* src_e = (dir == 0) ? eiN : eiE;
            if (dir == 0)
                gather_init<false, false, BF16AGG><<<25000, 256, 0, stream>>>(
                    nx, ori_node, eps_g + cj0, Xb, agg, M_COPIES);
            else
                gather_init<true, true, BF16AGG><<<25000, 256, 0, stream>>>(
                    accU, ori_edge, eps_g + cj0, Xb, agg, M_COPIES);

            for (int l = 0; l < 2; ++l) {
                int cj = cj0 + l;
                if (BF16AGG)
                    scatter_edges_pk<<<L_EDGES * 64 / 256, 256, 0, stream>>>(
                        src_e, src_e + L_EDGES, Xb, (unsigned short*)agg, L_EDGES);
                else
                    scatter_edges_f32<<<L_EDGES * 128 / 256, 256, 0, stream>>>(
                        src_e, src_e + L_EDGES, Xb, (float*)agg, L_EDGES);
                // linear1 + ReLU: agg -> Xb
                gemm128<!BF16AGG, 0, false, true><<<M_COPIES / 64, 256, 0, stream>>>(
                    agg, Wt + (size_t)(1 + cj * 2 + 0) * 16384, bg + (cj * 2 + 0) * 128,
                    nullptr, nullptr, nullptr, Xb, nullptr, M_COPIES);
                // linear2 + BN (+ReLU if mid): Xb -> Xb in-place (+ agg refresh)
                if (l == 0)
                    gemm128<false, (BF16AGG ? 2 : 1), true, true><<<M_COPIES / 64, 256, 0, stream>>>(
                        Xb, Wt + (size_t)(1 + cj * 2 + 1) * 16384, bg + (cj * 2 + 1) * 128,
                        gam + cj * 128, bet + cj * 128, eps_g + cj + 1,
                        Xb, agg, M_COPIES);
                else
                    gemm128<false, 0, true, false><<<M_COPIES / 64, 256, 0, stream>>>(
                        Xb, Wt + (size_t)(1 + cj * 2 + 1) * 16384, bg + (cj * 2 + 1) * 128,
                        gam + cj * 128, bet + cj * 128, nullptr,
                        Xb, nullptr, M_COPIES);
            }

            if (dir == 0) {
                (void)hipMemsetAsync(accU, 0, (size_t)N_EDGES * 128 * 4, stream);
                pool_scatter<<<M_COPIES * 128 / 256, 256, 0, stream>>>(
                    Xb, node2edge, accU, M_COPIES);
            } else {
                (void)hipMemsetAsync(accU, 0, (size_t)N_NODES * 128 * 4, stream);
                pool_scatter<<<M_COPIES * 128 / 256, 256, 0, stream>>>(
                    Xb, edge2node, accU, M_COPIES);
                relu_bf16<<<3125, 256, 0, stream>>>(accU, nx, N_NODES * 128 / 8);
                proj_y<true><<<(N_NODES + 255) / 256, 256, 0, stream>>>(
                    nx, Wp + (layer + 1) * HID * NCLS, y, N_NODES);
            }
        }
    }
    score_scatter<<<256, 256, 0, stream>>>(y, ori_node, batch, score);
    score_final<<<1, 320, 0, stream>>>(score, bp, d_out);
}

// ---------------- entry ----------------
extern "C" void kernel_launch(void* const* d_in, const int* in_sizes, int n_in,
                              void* d_out, int out_size, void* d_ws, size_t ws_size,
                              hipStream_t stream) {
    const size_t base = (size_t)17 * 16384 * 2                 // Wt
                      + (size_t)M_COPIES * 128 * 2             // Xb
                      + (size_t)N_NODES * 128 * 2              // nx
                      + (size_t)N_NODES * 128 * 4              // accU
                      + (size_t)N_NODES * NCLS * 4             // y
                      + (size_t)NBATCH * NCLS * 4;             // score
    const size_t need_bf16 = base + (size_t)M_COPIES * 128 * 2;  // ~246 MB
    // prefer bf16-agg (halves agg traffic); f32 fallback is one line away
    if (ws_size >= need_bf16)
        run_pipeline<true>(d_in, (char*)d_ws, (float*)d_out, stream);
    else
        fill_sentinel<<<(out_size + 63) / 64, 64, 0, stream>>>(
            (float*)d_out, out_size, 1.0e9f + (float)ws_size);
}

// Round 6
// 2979.291 us; speedup vs baseline: 1.5462x; 1.2900x over previous
//
#include <hip/hip_runtime.h>
#include <hip/hip_bf16.h>

// ---------------- problem constants ----------------
#define HID 128
static const int N_NODES = 50000;
static const int N_EDGES = 20000;
static const int M_COPIES = 400000;
static const int L_EDGES = 800000;
static const int NBATCH = 32;
static const int NCLS = 10;
#define INV_STD 0.9999950000374997f   // 1/sqrt(1+1e-5)

typedef __attribute__((ext_vector_type(4))) float f32x4;
typedef __attribute__((ext_vector_type(8))) short short8;      // 8 bf16 lanes
typedef __attribute__((ext_vector_type(8))) unsigned short ushort8;

__device__ __forceinline__ float bf2f(unsigned short u) {
    union { unsigned u; float f; } v; v.u = ((unsigned)u) << 16; return v.f;
}
__device__ __forceinline__ unsigned short f2bf(float f) {
    union { float f; unsigned u; } v; v.f = f;
    unsigned r = v.u + 0x7FFFu + ((v.u >> 16) & 1u);   // RNE
    return (unsigned short)(r >> 16);
}
__device__ __forceinline__ void gatomic_add(float* p, float v) {
    unsafeAtomicAdd(p, v);
}

// ---------------- weight prep: Wt[mat][n][k] = bf16(W[mat][k][n]) ----------------
__global__ __launch_bounds__(256) void prep_w(const float* __restrict__ We,
                                              const float* __restrict__ Wg,
                                              unsigned short* __restrict__ Wt) {
    int t = blockIdx.x * 256 + threadIdx.x;       // 17*16384
    if (t >= 17 * 16384) return;
    int mat = t >> 14, rem = t & 16383;
    int n = rem >> 7, k = rem & 127;
    const float* src = (mat == 0) ? We : (Wg + (size_t)(mat - 1) * 16384);
    Wt[t] = f2bf(src[k * 128 + n]);
}

// ---------------- CSR build: histogram -> exclusive scan -> atomic fill ----------------
// After fill, off[d] holds the inclusive end of segment d; segment d spans
// [d==0 ? 0 : off[d-1], off[d]).  (cursor-free trick)
__global__ __launch_bounds__(256) void hist_k(const int* __restrict__ idx, int n,
                                              int* __restrict__ cnt) {
    int t = blockIdx.x * 256 + threadIdx.x;
    if (t < n) atomicAdd(&cnt[idx[t]], 1);
}

// per-block exclusive scan of 256 elements; part[b] = block total
__global__ __launch_bounds__(256) void scan1_k(int* __restrict__ a, int n,
                                               int* __restrict__ part) {
    __shared__ int s[256];
    int i = blockIdx.x * 256 + threadIdx.x;
    int v = (i < n) ? a[i] : 0;
    s[threadIdx.x] = v;
    __syncthreads();
#pragma unroll
    for (int d = 1; d < 256; d <<= 1) {
        int t = (threadIdx.x >= d) ? s[threadIdx.x - d] : 0;
        __syncthreads();
        s[threadIdx.x] += t;
        __syncthreads();
    }
    if (i < n) a[i] = s[threadIdx.x] - v;           // exclusive within block
    if (threadIdx.x == 255) part[blockIdx.x] = s[255];
}

// single-block exclusive scan of part[0..nb)
__global__ __launch_bounds__(256) void scan2_k(int* __restrict__ part, int nb) {
    __shared__ int s[256];
    __shared__ int carry;
    if (threadIdx.x == 0) carry = 0;
    __syncthreads();
    for (int base = 0; base < nb; base += 256) {
        int i = base + threadIdx.x;
        int v = (i < nb) ? part[i] : 0;
        s[threadIdx.x] = v;
        __syncthreads();
#pragma unroll
        for (int d = 1; d < 256; d <<= 1) {
            int t = (threadIdx.x >= d) ? s[threadIdx.x - d] : 0;
            __syncthreads();
            s[threadIdx.x] += t;
            __syncthreads();
        }
        if (i < nb) part[i] = carry + s[threadIdx.x] - v;
        __syncthreads();
        if (threadIdx.x == 0) carry += s[255];
        __syncthreads();
    }
}

__global__ __launch_bounds__(256) void scan3_k(int* __restrict__ a, int n,
                                               const int* __restrict__ part) {
    int i = blockIdx.x * 256 + threadIdx.x;
    if (i < n) a[i] += part[blockIdx.x];
}

// edge CSR fill: payload = src copy index + composed ori[src]
__global__ __launch_bounds__(256) void fill_edge_k(
    const int* __restrict__ src, const int* __restrict__ dst,
    const int* __restrict__ remap, int n, int* __restrict__ off,
    int* __restrict__ srcs, int* __restrict__ comps) {
    int e = blockIdx.x * 256 + threadIdx.x;
    if (e >= n) return;
    int d = dst[e];
    int pos = atomicAdd(&off[d], 1);
    int s = src[e];
    srcs[pos] = s;
    comps[pos] = remap[s];
}

// pool CSR fill: payload = row index m
__global__ __launch_bounds__(256) void fill_pool_k(
    const int* __restrict__ seg, int n, int* __restrict__ off,
    int* __restrict__ items) {
    int m = blockIdx.x * 256 + threadIdx.x;
    if (m >= n) return;
    int pos = atomicAdd(&off[seg[m]], 1);
    items[pos] = m;
}

// ---------------- segment sum (wave per segment, dword=2ch per lane) ----------------
// MODE 0: out[m] = (1+eps)*tbl[self_idx[m]] + sum tbl[items[...]]   (GIN conv0)
// MODE 1: out[m] = (1+eps)*tbl[m]           + sum tbl[items[...]]   (GIN conv1)
// MODE 2: out[m] = relu(sum tbl[items[...]])                        (pooling)
template<int MODE>
__global__ __launch_bounds__(256) void segsum_k(
    const unsigned* __restrict__ tbl,        // bf16x2 rows [*,64]
    const int* __restrict__ self_idx,
    const int* __restrict__ off,
    const int* __restrict__ items,
    const float* __restrict__ eps_ptr,
    unsigned* __restrict__ out, int nseg)
{
    int wave = threadIdx.x >> 6, lane = threadIdx.x & 63;
    int m = blockIdx.x * 4 + wave;
    if (m >= nseg) return;
    int start = (m == 0) ? 0 : off[m - 1];
    int end = off[m];
    float a0 = 0.f, a1 = 0.f;
    if (MODE < 2) {
        float e = 1.0f + eps_ptr[0];
        int self = (MODE == 0) ? self_idx[m] : m;
        unsigned u = tbl[(size_t)self * 64 + lane];
        a0 = e * bf2f((unsigned short)(u & 0xffffu));
        a1 = e * bf2f((unsigned short)(u >> 16));
    }
    for (int pos = start; pos < end; ++pos) {
        int r = items[pos];
        unsigned u = tbl[(size_t)r * 64 + lane];
        a0 += bf2f((unsigned short)(u & 0xffffu));
        a1 += bf2f((unsigned short)(u >> 16));
    }
    if (MODE == 2) { a0 = fmaxf(a0, 0.f); a1 = fmaxf(a1, 0.f); }
    out[(size_t)m * 64 + lane] = (unsigned)f2bf(a0) | ((unsigned)f2bf(a1) << 16);
}

// ---------------- MFMA GEMM: h = act(in[rows,128] @ W + b) ----------------
// In-place (in == out_bf) safe: block reads its 64 rows to LDS, barrier, writes.
template<bool IN_F32, bool BN, bool RELU>
__global__ __launch_bounds__(256) void gemm128(
    const void* in, const unsigned short* __restrict__ Wt,
    const float* __restrict__ bias, const float* __restrict__ gammap,
    const float* __restrict__ betap, unsigned short* out_bf, int rows)
{
    __shared__ __align__(16) unsigned short Xs[16 * 64 * 8];
    __shared__ __align__(16) unsigned short Ws[16 * 128 * 8];
    int tid = threadIdx.x;
    int row0 = blockIdx.x * 64;

#pragma unroll
    for (int i = 0; i < 8; ++i) {          // stage W: 2048 chunks of 16B
        int chunk = tid + i * 256;
        int n = chunk >> 4, g = chunk & 15;
        short8 v = *(const short8*)(Wt + n * 128 + g * 8);
        *(short8*)(Ws + (g * 128 + n) * 8) = v;
    }
#pragma unroll
    for (int i = 0; i < 4; ++i) {          // stage X: 64 rows x 16 chunks
        int chunk = tid + i * 256;
        int r = chunk >> 4, g = chunk & 15;
        int gr = row0 + r;
        ushort8 v;
        if (gr < rows) {
            if (IN_F32) {
                const float* p = (const float*)in + (size_t)gr * 128 + g * 8;
                f32x4 a0 = *(const f32x4*)p;
                f32x4 a1 = *(const f32x4*)(p + 4);
#pragma unroll
                for (int j = 0; j < 4; ++j) { v[j] = f2bf(a0[j]); v[4 + j] = f2bf(a1[j]); }
            } else {
                v = *(const ushort8*)((const unsigned short*)in + (size_t)gr * 128 + g * 8);
            }
        } else {
#pragma unroll
            for (int j = 0; j < 8; ++j) v[j] = 0;
        }
        *(ushort8*)(Xs + (g * 64 + r) * 8) = v;
    }
    __syncthreads();

    int wave = tid >> 6, lane = tid & 63;
    int m0 = wave * 16;
    int ln = lane & 15, quad = lane >> 4;

    f32x4 acc[8];
#pragma unroll
    for (int t = 0; t < 8; ++t) acc[t] = (f32x4){0.f, 0.f, 0.f, 0.f};

#pragma unroll
    for (int kc = 0; kc < 4; ++kc) {
        int g = kc * 4 + quad;
        short8 a = *(const short8*)(Xs + (g * 64 + m0 + ln) * 8);
#pragma unroll
        for (int t = 0; t < 8; ++t) {
            short8 b = *(const short8*)(Ws + (g * 128 + t * 16 + ln) * 8);
            acc[t] = __builtin_amdgcn_mfma_f32_16x16x32_bf16(a, b, acc[t], 0, 0, 0);
        }
    }

#pragma unroll
    for (int t = 0; t < 8; ++t) {
        int col = t * 16 + ln;
        float bi = bias[col];
        float ga = BN ? gammap[col] : 0.f;
        float bb = BN ? betap[col] : 0.f;
#pragma unroll
        for (int i = 0; i < 4; ++i) {
            int gr = row0 + m0 + quad * 4 + i;   // C/D: row=(lane>>4)*4+reg, col=lane&15
            if (gr < rows) {
                float h = acc[t][i] + bi;
                if (BN) h = ga * h * INV_STD + bb;
                if (RELU) h = fmaxf(h, 0.f);
                out_bf[(size_t)gr * 128 + col] = f2bf(h);
            }
        }
    }
}

// ---------------- y projection: y[r][10] (+)= nx[r][:] @ Wp ----------------
template<bool ACCUM>
__global__ __launch_bounds__(256) void proj_y(
    const unsigned short* __restrict__ nx, const float* __restrict__ Wp,
    float* __restrict__ y, int rows)
{
    __shared__ float Wl[HID * NCLS];
    for (int i = threadIdx.x; i < HID * NCLS; i += 256) Wl[i] = Wp[i];
    __syncthreads();
    int r = blockIdx.x * 256 + threadIdx.x;
    if (r >= rows) return;
    float acc[NCLS];
#pragma unroll
    for (int c = 0; c < NCLS; ++c) acc[c] = 0.f;
    const unsigned short* xp = nx + (size_t)r * 128;
#pragma unroll 4
    for (int g = 0; g < 16; ++g) {
        ushort8 u = *(const ushort8*)(xp + g * 8);
#pragma unroll
        for (int j = 0; j < 8; ++j) {
            float xv = bf2f(u[j]);
            const float* w = Wl + (g * 8 + j) * NCLS;
#pragma unroll
            for (int c = 0; c < NCLS; ++c) acc[c] += xv * w[c];
        }
    }
    float* yp = y + (size_t)r * NCLS;
#pragma unroll
    for (int c = 0; c < NCLS; ++c) {
        if (ACCUM) yp[c] += acc[c];
        else yp[c] = acc[c];
    }
}

// ---------------- score scatter: score[b][:] += y[ori[m]][:] ----------------
__global__ __launch_bounds__(256) void score_scatter(
    const float* __restrict__ y, const int* __restrict__ ori,
    const int* __restrict__ batch, float* __restrict__ score)
{
    __shared__ float sc[NBATCH * NCLS];
    for (int i = threadIdx.x; i < NBATCH * NCLS; i += 256) sc[i] = 0.f;
    __syncthreads();
    int stride = gridDim.x * 256;
    for (int m = blockIdx.x * 256 + threadIdx.x; m < M_COPIES; m += stride) {
        int r = ori[m], b = batch[m];
        const float* yp = y + (size_t)r * NCLS;
#pragma unroll
        for (int c = 0; c < NCLS; ++c)
            __hip_atomic_fetch_add(&sc[b * NCLS + c], yp[c],
                                   __ATOMIC_RELAXED, __HIP_MEMORY_SCOPE_WORKGROUP);
    }
    __syncthreads();
    for (int i = threadIdx.x; i < NBATCH * NCLS; i += 256) gatomic_add(score + i, sc[i]);
}

__global__ void score_final(const float* __restrict__ score, const float* __restrict__ bp,
                            float* __restrict__ out)
{
    int t = threadIdx.x;
    if (t >= NBATCH * NCLS) return;
    int c = t % NCLS;
    out[t] = score[t] + bp[c] + bp[NCLS + c] + bp[2 * NCLS + c];
}

// sentinel: absmax ≈ 1e9 + ws_size  → decodes the actual workspace size
__global__ void fill_sentinel(float* out, int n, float enc) {
    int t = blockIdx.x * 64 + threadIdx.x;
    if (t < n) out[t] = enc;
}

// ---------------- helpers ----------------
static inline void build_csr_edge(const int* src, const int* dst, const int* remap,
                                  int nitem, int nseg, int* off, int* part,
                                  int* srcs, int* comps, hipStream_t stream) {
    int nb = (nseg + 255) / 256;
    (void)hipMemsetAsync(off, 0, (size_t)nseg * 4, stream);
    hist_k<<<(nitem + 255) / 256, 256, 0, stream>>>(dst, nitem, off);
    scan1_k<<<nb, 256, 0, stream>>>(off, nseg, part);
    scan2_k<<<1, 256, 0, stream>>>(part, nb);
    scan3_k<<<nb, 256, 0, stream>>>(off, nseg, part);
    fill_edge_k<<<(nitem + 255) / 256, 256, 0, stream>>>(src, dst, remap, nitem, off, srcs, comps);
}
static inline void build_csr_pool(const int* seg, int nitem, int nseg,
                                  int* off, int* part, int* items, hipStream_t stream) {
    int nb = (nseg + 255) / 256;
    (void)hipMemsetAsync(off, 0, (size_t)nseg * 4, stream);
    hist_k<<<(nitem + 255) / 256, 256, 0, stream>>>(seg, nitem, off);
    scan1_k<<<nb, 256, 0, stream>>>(off, nseg, part);
    scan2_k<<<1, 256, 0, stream>>>(part, nb);
    scan3_k<<<nb, 256, 0, stream>>>(off, nseg, part);
    fill_pool_k<<<(nitem + 255) / 256, 256, 0, stream>>>(seg, nitem, off, items);
}

// ---------------- entry ----------------
extern "C" void kernel_launch(void* const* d_in, const int* in_sizes, int n_in,
                              void* d_out, int out_size, void* d_ws, size_t ws_size,
                              hipStream_t stream) {
    const float* x_N    = (const float*)d_in[0];
    const float* We     = (const float*)d_in[1];
    const float* be     = (const float*)d_in[2];
    const float* Wg     = (const float*)d_in[3];
    const float* bg     = (const float*)d_in[4];
    const float* eps_g  = (const float*)d_in[5];
    const float* gam    = (const float*)d_in[6];
    const float* bet    = (const float*)d_in[7];
    const float* Wp     = (const float*)d_in[8];
    const float* bp     = (const float*)d_in[9];
    const int* ori_node = (const int*)d_in[10];
    const int* node2edge= (const int*)d_in[11];
    const int* eiN      = (const int*)d_in[12];
    const int* ori_edge = (const int*)d_in[13];
    const int* edge2node= (const int*)d_in[14];
    const int* eiE      = (const int*)d_in[15];
    const int* batch    = (const int*)d_in[16];

    char* p = (char*)d_ws;
    auto take = [&](size_t n) { char* r = p; p += (n + 255) & ~(size_t)255; return r; };
    unsigned short* Wt = (unsigned short*)take((size_t)17 * 16384 * 2);      // 0.56 MB
    unsigned short* Xb = (unsigned short*)take((size_t)M_COPIES * 128 * 2);  // 102.4 MB
    unsigned short* agg= (unsigned short*)take((size_t)M_COPIES * 128 * 2);  // 102.4 MB
    unsigned short* nx = (unsigned short*)take((size_t)N_NODES * 128 * 2);   // 12.8 MB
    unsigned short* ex = (unsigned short*)take((size_t)N_EDGES * 128 * 2);   // 5.12 MB
    float* y           = (float*)take((size_t)N_NODES * NCLS * 4);           // 2 MB
    float* score       = (float*)take((size_t)NBATCH * NCLS * 4);
    int* offN          = (int*)take((size_t)M_COPIES * 4);                   // 1.6 MB
    int* offE          = (int*)take((size_t)M_COPIES * 4);                   // 1.6 MB
    int* off_n2e       = (int*)take((size_t)N_EDGES * 4);
    int* off_e2n       = (int*)take((size_t)N_NODES * 4);
    int* srcsN         = (int*)take((size_t)L_EDGES * 4);                    // 3.2 MB
    int* compsN        = (int*)take((size_t)L_EDGES * 4);
    int* srcsE         = (int*)take((size_t)L_EDGES * 4);
    int* compsE        = (int*)take((size_t)L_EDGES * 4);
    int* it_n2e        = (int*)take((size_t)M_COPIES * 4);                   // 1.6 MB
    int* it_e2n        = (int*)take((size_t)M_COPIES * 4);
    int* part          = (int*)take((size_t)2048 * 4);
    size_t need = (size_t)(p - (char*)d_ws);
    if (need > ws_size) {
        fill_sentinel<<<(out_size + 63) / 64, 64, 0, stream>>>(
            (float*)d_out, out_size, 1.0e9f + (float)ws_size);
        return;
    }

    prep_w<<<1088, 256, 0, stream>>>(We, Wg, Wt);
    (void)hipMemsetAsync(score, 0, (size_t)NBATCH * NCLS * 4, stream);

    // CSR builds (amortized over both layers)
    build_csr_edge(eiN, eiN + L_EDGES, ori_node, L_EDGES, M_COPIES, offN, part, srcsN, compsN, stream);
    build_csr_edge(eiE, eiE + L_EDGES, ori_edge, L_EDGES, M_COPIES, offE, part, srcsE, compsE, stream);
    build_csr_pool(node2edge, M_COPIES, N_EDGES, off_n2e, part, it_n2e, stream);
    build_csr_pool(edge2node, M_COPIES, N_NODES, off_e2n, part, it_e2n, stream);

    // embedding: nx = x_N @ We + be ; y = nx @ Wp0
    gemm128<true, false, false><<<(N_NODES + 63) / 64, 256, 0, stream>>>(
        x_N, Wt, be, nullptr, nullptr, nx, N_NODES);
    proj_y<false><<<(N_NODES + 255) / 256, 256, 0, stream>>>(nx, Wp, y, N_NODES);

    for (int layer = 0; layer < 2; ++layer) {
        for (int dir = 0; dir < 2; ++dir) {
            int cj0 = layer * 4 + dir * 2;
            const unsigned* base = (dir == 0) ? (const unsigned*)nx : (const unsigned*)ex;
            const int* selfI = (dir == 0) ? ori_node : ori_edge;
            const int* offD  = (dir == 0) ? offN : offE;
            const int* srcsD = (dir == 0) ? srcsN : srcsE;
            const int* compD = (dir == 0) ? compsN : compsE;

            // conv0: agg = (1+eps0)*base[self] + sum base[comp]
            segsum_k<0><<<(M_COPIES + 3) / 4, 256, 0, stream>>>(
                base, selfI, offD, compD, eps_g + cj0, (unsigned*)agg, M_COPIES);
            gemm128<false, false, true><<<M_COPIES / 64, 256, 0, stream>>>(
                agg, Wt + (size_t)(1 + cj0 * 2) * 16384, bg + (cj0 * 2) * 128,
                nullptr, nullptr, Xb, M_COPIES);
            gemm128<false, true, true><<<M_COPIES / 64, 256, 0, stream>>>(
                Xb, Wt + (size_t)(1 + cj0 * 2 + 1) * 16384, bg + (cj0 * 2 + 1) * 128,
                gam + cj0 * 128, bet + cj0 * 128, Xb, M_COPIES);
            // conv1: agg = (1+eps1)*Xb + sum Xb[srcs]
            int cj1 = cj0 + 1;
            segsum_k<1><<<(M_COPIES + 3) / 4, 256, 0, stream>>>(
                (const unsigned*)Xb, nullptr, offD, srcsD, eps_g + cj1, (unsigned*)agg, M_COPIES);
            gemm128<false, false, true><<<M_COPIES / 64, 256, 0, stream>>>(
                agg, Wt + (size_t)(1 + cj1 * 2) * 16384, bg + (cj1 * 2) * 128,
                nullptr, nullptr, Xb, M_COPIES);
            gemm128<false, true, false><<<M_COPIES / 64, 256, 0, stream>>>(
                Xb, Wt + (size_t)(1 + cj1 * 2 + 1) * 16384, bg + (cj1 * 2 + 1) * 128,
                gam + cj1 * 128, bet + cj1 * 128, Xb, M_COPIES);
            // pool
            if (dir == 0) {
                segsum_k<2><<<(N_EDGES + 3) / 4, 256, 0, stream>>>(
                    (const unsigned*)Xb, nullptr, off_n2e, it_n2e, nullptr,
                    (unsigned*)ex, N_EDGES);
            } else {
                segsum_k<2><<<(N_NODES + 3) / 4, 256, 0, stream>>>(
                    (const unsigned*)Xb, nullptr, off_e2n, it_e2n, nullptr,
                    (unsigned*)nx, N_NODES);
                proj_y<true><<<(N_NODES + 255) / 256, 256, 0, stream>>>(
                    nx, Wp + (layer + 1) * HID * NCLS, y, N_NODES);
            }
        }
    }
    score_scatter<<<256, 256, 0, stream>>>(y, ori_node, batch, score);
    score_final<<<1, 320, 0, stream>>>(score, bp, (float*)d_out);
}

// Round 7
// 1959.020 us; speedup vs baseline: 2.3514x; 1.5208x over previous
//
#include <hip/hip_runtime.h>
#include <hip/hip_bf16.h>

// ---------------- problem constants ----------------
#define HID 128
static const int N_NODES = 50000;
static const int N_EDGES = 20000;
static const int M_COPIES = 400000;
static const int L_EDGES = 800000;
static const int NBATCH = 32;
static const int NCLS = 10;
#define INV_STD 0.9999950000374997f   // 1/sqrt(1+1e-5)

typedef __attribute__((ext_vector_type(4))) float f32x4;
typedef __attribute__((ext_vector_type(8))) short short8;      // 8 bf16 lanes
typedef __attribute__((ext_vector_type(8))) unsigned short ushort8;

__device__ __forceinline__ float bf2f(unsigned short u) {
    union { unsigned u; float f; } v; v.u = ((unsigned)u) << 16; return v.f;
}
__device__ __forceinline__ unsigned short f2bf(float f) {
    union { float f; unsigned u; } v; v.f = f;
    unsigned r = v.u + 0x7FFFu + ((v.u >> 16) & 1u);   // RNE
    return (unsigned short)(r >> 16);
}
__device__ __forceinline__ void gatomic_add(float* p, float v) {
    unsafeAtomicAdd(p, v);
}

// ---------------- weight prep: Wt[mat][n][k] = bf16(W[mat][k][n]) ----------------
__global__ __launch_bounds__(256) void prep_w(const float* __restrict__ We,
                                              const float* __restrict__ Wg,
                                              unsigned short* __restrict__ Wt) {
    int t = blockIdx.x * 256 + threadIdx.x;       // 17*16384
    if (t >= 17 * 16384) return;
    int mat = t >> 14, rem = t & 16383;
    int n = rem >> 7, k = rem & 127;
    const float* src = (mat == 0) ? We : (Wg + (size_t)(mat - 1) * 16384);
    Wt[t] = f2bf(src[k * 128 + n]);
}

// ---------------- CSR build: histogram -> exclusive scan -> atomic fill ----------------
// After fill, off[d] holds the inclusive end of segment d: [d? off[d-1]:0, off[d]).
__global__ __launch_bounds__(256) void hist_k(const int* __restrict__ idx, int n,
                                              int* __restrict__ cnt) {
    int t = blockIdx.x * 256 + threadIdx.x;
    if (t < n) atomicAdd(&cnt[idx[t]], 1);
}

__global__ __launch_bounds__(256) void scan1_k(int* __restrict__ a, int n,
                                               int* __restrict__ part) {
    __shared__ int s[256];
    int i = blockIdx.x * 256 + threadIdx.x;
    int v = (i < n) ? a[i] : 0;
    s[threadIdx.x] = v;
    __syncthreads();
#pragma unroll
    for (int d = 1; d < 256; d <<= 1) {
        int t = (threadIdx.x >= d) ? s[threadIdx.x - d] : 0;
        __syncthreads();
        s[threadIdx.x] += t;
        __syncthreads();
    }
    if (i < n) a[i] = s[threadIdx.x] - v;
    if (threadIdx.x == 255) part[blockIdx.x] = s[255];
}

__global__ __launch_bounds__(256) void scan2_k(int* __restrict__ part, int nb) {
    __shared__ int s[256];
    __shared__ int carry;
    if (threadIdx.x == 0) carry = 0;
    __syncthreads();
    for (int base = 0; base < nb; base += 256) {
        int i = base + threadIdx.x;
        int v = (i < nb) ? part[i] : 0;
        s[threadIdx.x] = v;
        __syncthreads();
#pragma unroll
        for (int d = 1; d < 256; d <<= 1) {
            int t = (threadIdx.x >= d) ? s[threadIdx.x - d] : 0;
            __syncthreads();
            s[threadIdx.x] += t;
            __syncthreads();
        }
        if (i < nb) part[i] = carry + s[threadIdx.x] - v;
        __syncthreads();
        if (threadIdx.x == 0) carry += s[255];
        __syncthreads();
    }
}

__global__ __launch_bounds__(256) void scan3_k(int* __restrict__ a, int n,
                                               const int* __restrict__ part) {
    int i = blockIdx.x * 256 + threadIdx.x;
    if (i < n) a[i] += part[blockIdx.x];
}

__global__ __launch_bounds__(256) void fill_edge_k(
    const int* __restrict__ src, const int* __restrict__ dst,
    const int* __restrict__ remap, int n, int* __restrict__ off,
    int* __restrict__ srcs, int* __restrict__ comps) {
    int e = blockIdx.x * 256 + threadIdx.x;
    if (e >= n) return;
    int d = dst[e];
    int pos = atomicAdd(&off[d], 1);
    int s = src[e];
    srcs[pos] = s;
    comps[pos] = remap[s];
}

__global__ __launch_bounds__(256) void fill_pool_k(
    const int* __restrict__ seg, int n, int* __restrict__ off,
    int* __restrict__ items) {
    int m = blockIdx.x * 256 + threadIdx.x;
    if (m >= n) return;
    int pos = atomicAdd(&off[seg[m]], 1);
    items[pos] = m;
}

// ---------------- pool segment sum: out[m] = relu(sum tbl[items]) ----------------
__global__ __launch_bounds__(256) void segsum_pool(
    const unsigned* __restrict__ tbl, const int* __restrict__ off,
    const int* __restrict__ items, unsigned* __restrict__ out, int nseg)
{
    int wave = threadIdx.x >> 6, lane = threadIdx.x & 63;
    int m = blockIdx.x * 4 + wave;
    if (m >= nseg) return;
    int start = (m == 0) ? 0 : off[m - 1];
    int end = off[m];
    float a0 = 0.f, a1 = 0.f;
    for (int pos = start; pos < end; ++pos) {
        int r = items[pos];
        unsigned u = tbl[(size_t)r * 64 + lane];
        a0 += bf2f((unsigned short)(u & 0xffffu));
        a1 += bf2f((unsigned short)(u >> 16));
    }
    a0 = fmaxf(a0, 0.f); a1 = fmaxf(a1, 0.f);
    out[(size_t)m * 64 + lane] = (unsigned)f2bf(a0) | ((unsigned)f2bf(a1) << 16);
}

// ---------------- fused GIN conv: segsum-gather + linear1+ReLU + linear2+BN(+ReLU) ----------------
// CONV0: self = self_idx[m] into tbl (base table), items = comps into tbl; ReLU after BN.
// !CONV0: self = own row m of tbl (=Xin), items = srcs into tbl; no final ReLU.
// rows must be a multiple of 64 (M_COPIES is).
template<bool CONV0>
__global__ __launch_bounds__(256) void fused_conv(
    const unsigned short* __restrict__ tbl,
    const int* __restrict__ self_idx,
    const int* __restrict__ off, const int* __restrict__ items,
    const float* __restrict__ eps_ptr,
    const unsigned short* __restrict__ W1t, const float* __restrict__ b1,
    const unsigned short* __restrict__ W2t, const float* __restrict__ b2,
    const float* __restrict__ gam, const float* __restrict__ bet,
    unsigned short* __restrict__ out)
{
    __shared__ __align__(16) unsigned short Xs[16 * 64 * 8];   // 16 KB
    __shared__ __align__(16) unsigned short Ws[16 * 128 * 8];  // 32 KB
    __shared__ int meta[192];
    int tid = threadIdx.x;
    int row0 = blockIdx.x * 64;

    if (tid < 64) {
        int gr = row0 + tid;
        meta[tid]       = (gr == 0) ? 0 : off[gr - 1];
        meta[64 + tid]  = off[gr];
        meta[128 + tid] = CONV0 ? self_idx[gr] : gr;
    }
    // stage W1
#pragma unroll
    for (int i = 0; i < 8; ++i) {
        int chunk = tid + i * 256;
        int n = chunk >> 4, g = chunk & 15;
        *(short8*)(Ws + (g * 128 + n) * 8) = *(const short8*)(W1t + n * 128 + g * 8);
    }
    __syncthreads();

    float e = 1.0f + eps_ptr[0];
    // stage X = (1+eps)*tbl[self] + sum tbl[items]  (f32 accumulate, bf16 to LDS)
#pragma unroll
    for (int i = 0; i < 4; ++i) {
        int chunk = tid + i * 256;
        int r = chunk >> 4, g = chunk & 15;
        int start = meta[r], end = meta[64 + r], self = meta[128 + r];
        float a[8];
        ushort8 u = *(const ushort8*)(tbl + (size_t)self * 128 + g * 8);
#pragma unroll
        for (int j = 0; j < 8; ++j) a[j] = e * bf2f(u[j]);
        for (int pos = start; pos < end; ++pos) {
            int rr = items[pos];
            ushort8 v = *(const ushort8*)(tbl + (size_t)rr * 128 + g * 8);
#pragma unroll
            for (int j = 0; j < 8; ++j) a[j] += bf2f(v[j]);
        }
        ushort8 xv;
#pragma unroll
        for (int j = 0; j < 8; ++j) xv[j] = f2bf(a[j]);
        *(ushort8*)(Xs + (g * 64 + r) * 8) = xv;
    }
    __syncthreads();

    int wave = tid >> 6, lane = tid & 63;
    int m0 = wave * 16;
    int ln = lane & 15, quad = lane >> 4;

    // ---- MFMA 1 ----
    f32x4 acc[8];
#pragma unroll
    for (int t = 0; t < 8; ++t) acc[t] = (f32x4){0.f, 0.f, 0.f, 0.f};
#pragma unroll
    for (int kc = 0; kc < 4; ++kc) {
        int g = kc * 4 + quad;
        short8 a = *(const short8*)(Xs + (g * 64 + m0 + ln) * 8);
#pragma unroll
        for (int t = 0; t < 8; ++t) {
            short8 b = *(const short8*)(Ws + (g * 128 + t * 16 + ln) * 8);
            acc[t] = __builtin_amdgcn_mfma_f32_16x16x32_bf16(a, b, acc[t], 0, 0, 0);
        }
    }
    // h = relu(acc + b1) -> Xs (wave-private rows m0..m0+15)
#pragma unroll
    for (int t = 0; t < 8; ++t) {
        int col = t * 16 + ln;
        float bi = b1[col];
        int gch = col >> 3, j = col & 7;
#pragma unroll
        for (int i = 0; i < 4; ++i) {
            int row = m0 + quad * 4 + i;
            float h = fmaxf(acc[t][i] + bi, 0.f);
            Xs[(gch * 64 + row) * 8 + j] = f2bf(h);
        }
    }
    __syncthreads();
    // stage W2 (overwrites Ws; all MFMA1 B-reads are done)
#pragma unroll
    for (int i = 0; i < 8; ++i) {
        int chunk = tid + i * 256;
        int n = chunk >> 4, g = chunk & 15;
        *(short8*)(Ws + (g * 128 + n) * 8) = *(const short8*)(W2t + n * 128 + g * 8);
    }
    __syncthreads();

    // ---- MFMA 2 ----
#pragma unroll
    for (int t = 0; t < 8; ++t) acc[t] = (f32x4){0.f, 0.f, 0.f, 0.f};
#pragma unroll
    for (int kc = 0; kc < 4; ++kc) {
        int g = kc * 4 + quad;
        short8 a = *(const short8*)(Xs + (g * 64 + m0 + ln) * 8);
#pragma unroll
        for (int t = 0; t < 8; ++t) {
            short8 b = *(const short8*)(Ws + (g * 128 + t * 16 + ln) * 8);
            acc[t] = __builtin_amdgcn_mfma_f32_16x16x32_bf16(a, b, acc[t], 0, 0, 0);
        }
    }
#pragma unroll
    for (int t = 0; t < 8; ++t) {
        int col = t * 16 + ln;
        float bi = b2[col];
        float ga = gam[col], bb = bet[col];
#pragma unroll
        for (int i = 0; i < 4; ++i) {
            int gr = row0 + m0 + quad * 4 + i;
            float h = acc[t][i] + bi;
            h = ga * h * INV_STD + bb;
            if (CONV0) h = fmaxf(h, 0.f);
            out[(size_t)gr * 128 + col] = f2bf(h);
        }
    }
}

// ---------------- embedding GEMM (f32 in): out = in @ W + b ----------------
__global__ __launch_bounds__(256) void gemm_embed(
    const float* __restrict__ in, const unsigned short* __restrict__ Wt,
    const float* __restrict__ bias, unsigned short* __restrict__ out_bf, int rows)
{
    __shared__ __align__(16) unsigned short Xs[16 * 64 * 8];
    __shared__ __align__(16) unsigned short Ws[16 * 128 * 8];
    int tid = threadIdx.x;
    int row0 = blockIdx.x * 64;
#pragma unroll
    for (int i = 0; i < 8; ++i) {
        int chunk = tid + i * 256;
        int n = chunk >> 4, g = chunk & 15;
        *(short8*)(Ws + (g * 128 + n) * 8) = *(const short8*)(Wt + n * 128 + g * 8);
    }
#pragma unroll
    for (int i = 0; i < 4; ++i) {
        int chunk = tid + i * 256;
        int r = chunk >> 4, g = chunk & 15;
        int gr = row0 + r;
        ushort8 v;
        if (gr < rows) {
            const float* p = in + (size_t)gr * 128 + g * 8;
            f32x4 a0 = *(const f32x4*)p;
            f32x4 a1 = *(const f32x4*)(p + 4);
#pragma unroll
            for (int j = 0; j < 4; ++j) { v[j] = f2bf(a0[j]); v[4 + j] = f2bf(a1[j]); }
        } else {
#pragma unroll
            for (int j = 0; j < 8; ++j) v[j] = 0;
        }
        *(ushort8*)(Xs + (g * 64 + r) * 8) = v;
    }
    __syncthreads();
    int wave = tid >> 6, lane = tid & 63;
    int m0 = wave * 16;
    int ln = lane & 15, quad = lane >> 4;
    f32x4 acc[8];
#pragma unroll
    for (int t = 0; t < 8; ++t) acc[t] = (f32x4){0.f, 0.f, 0.f, 0.f};
#pragma unroll
    for (int kc = 0; kc < 4; ++kc) {
        int g = kc * 4 + quad;
        short8 a = *(const short8*)(Xs + (g * 64 + m0 + ln) * 8);
#pragma unroll
        for (int t = 0; t < 8; ++t) {
            short8 b = *(const short8*)(Ws + (g * 128 + t * 16 + ln) * 8);
            acc[t] = __builtin_amdgcn_mfma_f32_16x16x32_bf16(a, b, acc[t], 0, 0, 0);
        }
    }
#pragma unroll
    for (int t = 0; t < 8; ++t) {
        int col = t * 16 + ln;
        float bi = bias[col];
#pragma unroll
        for (int i = 0; i < 4; ++i) {
            int gr = row0 + m0 + quad * 4 + i;
            if (gr < rows) out_bf[(size_t)gr * 128 + col] = f2bf(acc[t][i] + bi);
        }
    }
}

// ---------------- y projection: y[r][10] (+)= nx[r][:] @ Wp ----------------
template<bool ACCUM>
__global__ __launch_bounds__(256) void proj_y(
    const unsigned short* __restrict__ nx, const float* __restrict__ Wp,
    float* __restrict__ y, int rows)
{
    __shared__ float Wl[HID * NCLS];
    for (int i = threadIdx.x; i < HID * NCLS; i += 256) Wl[i] = Wp[i];
    __syncthreads();
    int r = blockIdx.x * 256 + threadIdx.x;
    if (r >= rows) return;
    float acc[NCLS];
#pragma unroll
    for (int c = 0; c < NCLS; ++c) acc[c] = 0.f;
    const unsigned short* xp = nx + (size_t)r * 128;
#pragma unroll 4
    for (int g = 0; g < 16; ++g) {
        ushort8 u = *(const ushort8*)(xp + g * 8);
#pragma unroll
        for (int j = 0; j < 8; ++j) {
            float xv = bf2f(u[j]);
            const float* w = Wl + (g * 8 + j) * NCLS;
#pragma unroll
            for (int c = 0; c < NCLS; ++c) acc[c] += xv * w[c];
        }
    }
    float* yp = y + (size_t)r * NCLS;
#pragma unroll
    for (int c = 0; c < NCLS; ++c) {
        if (ACCUM) yp[c] += acc[c];
        else yp[c] = acc[c];
    }
}

// ---------------- score scatter: score[b][:] += y[ori[m]][:] ----------------
__global__ __launch_bounds__(256) void score_scatter(
    const float* __restrict__ y, const int* __restrict__ ori,
    const int* __restrict__ batch, float* __restrict__ score)
{
    __shared__ float sc[NBATCH * NCLS];
    for (int i = threadIdx.x; i < NBATCH * NCLS; i += 256) sc[i] = 0.f;
    __syncthreads();
    int stride = gridDim.x * 256;
    for (int m = blockIdx.x * 256 + threadIdx.x; m < M_COPIES; m += stride) {
        int r = ori[m], b = batch[m];
        const float* yp = y + (size_t)r * NCLS;
#pragma unroll
        for (int c = 0; c < NCLS; ++c)
            __hip_atomic_fetch_add(&sc[b * NCLS + c], yp[c],
                                   __ATOMIC_RELAXED, __HIP_MEMORY_SCOPE_WORKGROUP);
    }
    __syncthreads();
    for (int i = threadIdx.x; i < NBATCH * NCLS; i += 256) gatomic_add(score + i, sc[i]);
}

__global__ void score_final(const float* __restrict__ score, const float* __restrict__ bp,
                            float* __restrict__ out)
{
    int t = threadIdx.x;
    if (t >= NBATCH * NCLS) return;
    int c = t % NCLS;
    out[t] = score[t] + bp[c] + bp[NCLS + c] + bp[2 * NCLS + c];
}

__global__ void fill_sentinel(float* out, int n, float enc) {
    int t = blockIdx.x * 64 + threadIdx.x;
    if (t < n) out[t] = enc;
}

// ---------------- helpers ----------------
static inline void build_csr_edge(const int* src, const int* dst, const int* remap,
                                  int nitem, int nseg, int* off, int* part,
                                  int* srcs, int* comps, hipStream_t stream) {
    int nb = (nseg + 255) / 256;
    (void)hipMemsetAsync(off, 0, (size_t)nseg * 4, stream);
    hist_k<<<(nitem + 255) / 256, 256, 0, stream>>>(dst, nitem, off);
    scan1_k<<<nb, 256, 0, stream>>>(off, nseg, part);
    scan2_k<<<1, 256, 0, stream>>>(part, nb);
    scan3_k<<<nb, 256, 0, stream>>>(off, nseg, part);
    fill_edge_k<<<(nitem + 255) / 256, 256, 0, stream>>>(src, dst, remap, nitem, off, srcs, comps);
}
static inline void build_csr_pool(const int* seg, int nitem, int nseg,
                                  int* off, int* part, int* items, hipStream_t stream) {
    int nb = (nseg + 255) / 256;
    (void)hipMemsetAsync(off, 0, (size_t)nseg * 4, stream);
    hist_k<<<(nitem + 255) / 256, 256, 0, stream>>>(seg, nitem, off);
    scan1_k<<<nb, 256, 0, stream>>>(off, nseg, part);
    scan2_k<<<1, 256, 0, stream>>>(part, nb);
    scan3_k<<<nb, 256, 0, stream>>>(off, nseg, part);
    fill_pool_k<<<(nitem + 255) / 256, 256, 0, stream>>>(seg, nitem, off, items);
}

// ---------------- entry ----------------
extern "C" void kernel_launch(void* const* d_in, const int* in_sizes, int n_in,
                              void* d_out, int out_size, void* d_ws, size_t ws_size,
                              hipStream_t stream) {
    const float* x_N    = (const float*)d_in[0];
    const float* We     = (const float*)d_in[1];
    const float* be     = (const float*)d_in[2];
    const float* Wg     = (const float*)d_in[3];
    const float* bg     = (const float*)d_in[4];
    const float* eps_g  = (const float*)d_in[5];
    const float* gam    = (const float*)d_in[6];
    const float* bet    = (const float*)d_in[7];
    const float* Wp     = (const float*)d_in[8];
    const float* bp     = (const float*)d_in[9];
    const int* ori_node = (const int*)d_in[10];
    const int* node2edge= (const int*)d_in[11];
    const int* eiN      = (const int*)d_in[12];
    const int* ori_edge = (const int*)d_in[13];
    const int* edge2node= (const int*)d_in[14];
    const int* eiE      = (const int*)d_in[15];
    const int* batch    = (const int*)d_in[16];

    char* p = (char*)d_ws;
    auto take = [&](size_t n) { char* r = p; p += (n + 255) & ~(size_t)255; return r; };
    unsigned short* Wt  = (unsigned short*)take((size_t)17 * 16384 * 2);
    unsigned short* Xb  = (unsigned short*)take((size_t)M_COPIES * 128 * 2);
    unsigned short* Xb2 = (unsigned short*)take((size_t)M_COPIES * 128 * 2);
    unsigned short* nx  = (unsigned short*)take((size_t)N_NODES * 128 * 2);
    unsigned short* ex  = (unsigned short*)take((size_t)N_EDGES * 128 * 2);
    float* y            = (float*)take((size_t)N_NODES * NCLS * 4);
    float* score        = (float*)take((size_t)NBATCH * NCLS * 4);
    int* offN           = (int*)take((size_t)M_COPIES * 4);
    int* offE           = (int*)take((size_t)M_COPIES * 4);
    int* off_n2e        = (int*)take((size_t)N_EDGES * 4);
    int* off_e2n        = (int*)take((size_t)N_NODES * 4);
    int* srcsN          = (int*)take((size_t)L_EDGES * 4);
    int* compsN         = (int*)take((size_t)L_EDGES * 4);
    int* srcsE          = (int*)take((size_t)L_EDGES * 4);
    int* compsE         = (int*)take((size_t)L_EDGES * 4);
    int* it_n2e         = (int*)take((size_t)M_COPIES * 4);
    int* it_e2n         = (int*)take((size_t)M_COPIES * 4);
    int* part           = (int*)take((size_t)2048 * 4);
    size_t need = (size_t)(p - (char*)d_ws);
    if (need > ws_size) {
        fill_sentinel<<<(out_size + 63) / 64, 64, 0, stream>>>(
            (float*)d_out, out_size, 1.0e9f + (float)ws_size);
        return;
    }

    prep_w<<<1088, 256, 0, stream>>>(We, Wg, Wt);
    (void)hipMemsetAsync(score, 0, (size_t)NBATCH * NCLS * 4, stream);

    build_csr_edge(eiN, eiN + L_EDGES, ori_node, L_EDGES, M_COPIES, offN, part, srcsN, compsN, stream);
    build_csr_edge(eiE, eiE + L_EDGES, ori_edge, L_EDGES, M_COPIES, offE, part, srcsE, compsE, stream);
    build_csr_pool(node2edge, M_COPIES, N_EDGES, off_n2e, part, it_n2e, stream);
    build_csr_pool(edge2node, M_COPIES, N_NODES, off_e2n, part, it_e2n, stream);

    gemm_embed<<<(N_NODES + 63) / 64, 256, 0, stream>>>(x_N, Wt, be, nx, N_NODES);
    proj_y<false><<<(N_NODES + 255) / 256, 256, 0, stream>>>(nx, Wp, y, N_NODES);

    const int MBLK = M_COPIES / 64;   // 6250
    for (int layer = 0; layer < 2; ++layer) {
        for (int dir = 0; dir < 2; ++dir) {
            int cj0 = layer * 4 + dir * 2;
            int cj1 = cj0 + 1;
            const unsigned short* base = (dir == 0) ? nx : ex;
            const int* selfI = (dir == 0) ? ori_node : ori_edge;
            const int* offD  = (dir == 0) ? offN : offE;
            const int* srcsD = (dir == 0) ? srcsN : srcsE;
            const int* compD = (dir == 0) ? compsN : compsE;

            // conv0: gather from base (LLC-resident) -> MLP -> Xb
            fused_conv<true><<<MBLK, 256, 0, stream>>>(
                base, selfI, offD, compD, eps_g + cj0,
                Wt + (size_t)(1 + cj0 * 2) * 16384, bg + (cj0 * 2) * 128,
                Wt + (size_t)(1 + cj0 * 2 + 1) * 16384, bg + (cj0 * 2 + 1) * 128,
                gam + cj0 * 128, bet + cj0 * 128, Xb);
            // conv1: gather from Xb -> MLP -> Xb2
            fused_conv<false><<<MBLK, 256, 0, stream>>>(
                Xb, nullptr, offD, srcsD, eps_g + cj1,
                Wt + (size_t)(1 + cj1 * 2) * 16384, bg + (cj1 * 2) * 128,
                Wt + (size_t)(1 + cj1 * 2 + 1) * 16384, bg + (cj1 * 2 + 1) * 128,
                gam + cj1 * 128, bet + cj1 * 128, Xb2);
            // pool (+ReLU)
            if (dir == 0) {
                segsum_pool<<<(N_EDGES + 3) / 4, 256, 0, stream>>>(
                    (const unsigned*)Xb2, off_n2e, it_n2e, (unsigned*)ex, N_EDGES);
            } else {
                segsum_pool<<<(N_NODES + 3) / 4, 256, 0, stream>>>(
                    (const unsigned*)Xb2, off_e2n, it_e2n, (unsigned*)nx, N_NODES);
                proj_y<true><<<(N_NODES + 255) / 256, 256, 0, stream>>>(
                    nx, Wp + (layer + 1) * HID * NCLS, y, N_NODES);
            }
        }
    }
    score_scatter<<<256, 256, 0, stream>>>(y, ori_node, batch, score);
    score_final<<<1, 320, 0, stream>>>(score, bp, (float*)d_out);
}